// Round 19
// baseline (2811.766 us; speedup 1.0000x reference)
//
#include <hip/hip_runtime.h>
#include <hip/hip_bf16.h>
#include <hip/hip_fp8.h>
#include <stdint.h>

typedef __hip_bfloat16 bf16_t;
typedef __attribute__((ext_vector_type(8))) short bf16x8;
typedef __attribute__((ext_vector_type(4))) float f32x4;

#define MU_DT 0.01f
#define S8 8.0f                  // fp8 operand pre-scale (escape subnormals)
#define INV_S64 (1.0f / 64.0f)   // descale after fp8xfp8 GEMM

__device__ inline uint8_t f2fp8(float x) {
  __hip_fp8_e4m3 t(x);           // OCP e4m3 on gfx950
  return t.__x;
}

__device__ inline void gload_lds16(const void* g, void* lds) {
  __builtin_amdgcn_global_load_lds((const __attribute__((address_space(1))) void*)g,
                                   (__attribute__((address_space(3))) void*)lds, 16, 0, 0);
}

struct Seg { int start, layer, tmBase, tilesN, nSub; };

// ======================= fp8 iteration kernel =======================
// R19 = R16's proven 2-slot 64x128/8-wave fp8 engine (LDS-BW roofline:
// 127 B/cy/CU measured vs 128 peak) + multi-tile sub-jobs for makespan.
// R18's counted-vmcnt/3-slot REGRESSED (72KiB LDS -> 2 blk/CU, occ 28%);
// reverted. fwd L0 (K=1024, 8 steps) merged 4 tiles/block -> all fwd jobs
// are uniform 32-step blocks, grid 512 = exactly 2/CU, makespan 72->64.
struct GemmLayer8 {
  const uint8_t* A;    // (512 x K) fp8(x8), row-major
  const uint8_t* Bt;   // (N x K) fp8(x8), row-major
  const float*  X;     // fwd: mu_{l+1}/img (f32); bwd: mu_l (f32)
  const float*  E;     // bwd l>0: e_l
  float*        O1;    // fwd: e out; bwd: mu out (f32 master)
  uint8_t*      O2a;   // fwd: G8 out; bwd: m8 out (fp8 x8)
  bf16_t*       O2b;   // bwd: mb out (bf16, for final pass)
  int K, N, mode;
};
struct GemmArgs8 { GemmLayer8 L[3]; Seg seg[8]; };

__global__ __launch_bounds__(512) void gemm_fp8(GemmArgs8 args) {
  __shared__ __align__(16) uint8_t As[2 * 64 * 128];    // 2 x 8 KiB
  __shared__ __align__(16) uint8_t Bs[2 * 128 * 128];   // 2 x 16 KiB

  const int bid = blockIdx.x;
  int s = 0;
#pragma unroll
  for (int i = 1; i < 8; ++i)
    if (bid >= args.seg[i].start) s = i;
  const Seg sg = args.seg[s];
  const GemmLayer8 Lr = args.L[sg.layer];
  const int local = bid - sg.start;
  const int tm = sg.tmBase + local / sg.tilesN;
  const int tn0 = local % sg.tilesN;
  const int K = Lr.K;
  const int rowBase = tm * 64;

  const int tid  = threadIdx.x;
  const int lane = tid & 63;
  const int wv   = tid >> 6;
  const int wrM  = wv >> 2;            // 0..1 -> 32-row band
  const int wcN  = wv & 3;             // 0..3 -> 32-col band
  const int lo   = lane & 15, hi = lane >> 4;

  char* AsB = (char*)As;   // halves at +0 / +8192
  char* BsB = (char*)Bs;   // halves at +0 / +16384

  // A staging (row depends only on tm) and read-side offsets: hoisted.
  const uint8_t* pA0;
  {
    const int c = tid;
    const int r = c >> 3, sw = (c & 7) ^ (r & 7);
    pA0 = Lr.A + (size_t)(rowBase + r) * K + sw * 16;
  }
  int aoff[2][4], boff[2][4];
#pragma unroll
  for (int m = 0; m < 2; ++m) {
    const int row = wrM * 32 + m * 16 + lo;
#pragma unroll
    for (int kk = 0; kk < 4; ++kk)
      aoff[m][kk] = row * 128 + (((kk * 2 + (hi >> 1)) ^ (row & 7)) << 4) + ((hi & 1) << 3);
  }
#pragma unroll
  for (int n = 0; n < 2; ++n) {
    const int row = wcN * 32 + n * 16 + lo;
#pragma unroll
    for (int kk = 0; kk < 4; ++kk)
      boff[n][kk] = row * 128 + (((kk * 2 + (hi >> 1)) ^ (row & 7)) << 4) + ((hi & 1) << 3);
  }

  const int waveB = wv * 1024;
  const int nkt = K >> 7;   // BK=128

  for (int sub = 0; sub < sg.nSub; ++sub) {
    if (sub) __syncthreads();   // guard LDS reuse across sub-jobs
    const int tn = tn0 + sub * sg.tilesN;
    const int colBase = tn * 128;

    const uint8_t* pB[2];
#pragma unroll
    for (int j = 0; j < 2; ++j) {
      const int c = j * 512 + tid;
      const int r = c >> 3, sw = (c & 7) ^ (r & 7);
      pB[j] = Lr.Bt + (size_t)(colBase + r) * K + sw * 16;
    }

    f32x4 acc[2][2];
#pragma unroll
    for (int m = 0; m < 2; ++m)
#pragma unroll
      for (int n = 0; n < 2; ++n)
        acc[m][n] = f32x4{0.f, 0.f, 0.f, 0.f};

    gload_lds16(pA0,   AsB + waveB);
    gload_lds16(pB[0], BsB + waveB);
    gload_lds16(pB[1], BsB + 8192 + waveB);
    __syncthreads();

    int cur = 0;
    for (int kt = 0; kt < nkt; ++kt) {
      const int curA = cur * 8192, curB = cur * 16384;
      if (kt + 1 < nkt) {
        const int ke = (kt + 1) * 128;
        gload_lds16(pA0 + ke,   AsB + (curA ^ 8192) + waveB);
        gload_lds16(pB[0] + ke, BsB + (curB ^ 16384) + waveB);
        gload_lds16(pB[1] + ke, BsB + (curB ^ 16384) + 8192 + waveB);
      }

      long a[2][4], b[2][4];
#pragma unroll
      for (int m = 0; m < 2; ++m)
#pragma unroll
        for (int kk = 0; kk < 4; ++kk)
          a[m][kk] = *(const long*)(AsB + curA + aoff[m][kk]);
#pragma unroll
      for (int n = 0; n < 2; ++n)
#pragma unroll
        for (int kk = 0; kk < 4; ++kk)
          b[n][kk] = *(const long*)(BsB + curB + boff[n][kk]);

#pragma unroll
      for (int kk = 0; kk < 4; ++kk)
#pragma unroll
        for (int m = 0; m < 2; ++m)
#pragma unroll
          for (int n = 0; n < 2; ++n)
            acc[m][n] = __builtin_amdgcn_mfma_f32_16x16x32_fp8_fp8(a[m][kk], b[n][kk], acc[m][n], 0, 0, 0);

      if (kt + 1 < nkt) {
        __syncthreads();
        cur ^= 1;
      }
    }

    // epilogue — C/D layout: col = lane&15, row = (lane>>4)*4 + reg
    const int N = Lr.N;
#pragma unroll
    for (int m = 0; m < 2; ++m) {
#pragma unroll
      for (int n = 0; n < 2; ++n) {
#pragma unroll
        for (int r = 0; r < 4; ++r) {
          const int row = rowBase + wrM * 32 + m * 16 + hi * 4 + r;
          const int col = colBase + wcN * 32 + n * 16 + lo;
          const float v = acc[m][n][r] * INV_S64;
          const size_t iN = (size_t)row * N + col;
          if (Lr.mode == 0) {
            const float mu = Lr.X[iN];
            const float t  = tanhf(v);
            const float e  = mu - t;
            Lr.O1[iN]  = e;
            Lr.O2a[iN] = f2fp8(e * (1.0f - t * t) * S8);
          } else if (Lr.mode == 1) {
            const float e = Lr.X[iN] - v;
            Lr.O1[iN]  = e;
            Lr.O2a[iN] = f2fp8(e * S8);
          } else {
            const float mu = Lr.X[iN];
            const float sub2 = (Lr.mode == 2) ? mu : Lr.E[iN];
            const float nv = mu + MU_DT * (v - sub2);
            Lr.O1[iN]  = nv;
            Lr.O2a[iN] = f2fp8(nv * S8);
            Lr.O2b[iN] = __float2bfloat16(nv);
          }
        }
      }
    }
  }
}

// ======================= bf16 final-pass kernel =======================
struct GemmLayer {
  const bf16_t* A;
  const bf16_t* Bt;
  const float*  X;
  float*        O1;
  int K, N, ostride, mode;
};
struct GemmArgs { GemmLayer L[3]; Seg seg[8]; };

__global__ __launch_bounds__(512) void gemm_bf16(GemmArgs args) {
  __shared__ __align__(16) bf16_t As[2 * 64 * 64];
  __shared__ __align__(16) bf16_t Bs[2 * 128 * 64];

  const int bid = blockIdx.x;
  int s = 0;
#pragma unroll
  for (int i = 1; i < 8; ++i)
    if (bid >= args.seg[i].start) s = i;
  const Seg sg = args.seg[s];
  const GemmLayer Lr = args.L[sg.layer];
  const int local = bid - sg.start;
  const int tm = sg.tmBase + local / sg.tilesN;
  const int tn = local % sg.tilesN;
  const int K = Lr.K;
  const int rowBase = tm * 64;
  const int colBase = tn * 128;

  const int tid  = threadIdx.x;
  const int lane = tid & 63;
  const int wv   = tid >> 6;
  const int wrM  = wv >> 2;
  const int wcN  = wv & 3;
  const int lo   = lane & 15, hi = lane >> 4;

  f32x4 acc[2][2];
#pragma unroll
  for (int m = 0; m < 2; ++m)
#pragma unroll
    for (int n = 0; n < 2; ++n)
      acc[m][n] = f32x4{0.f, 0.f, 0.f, 0.f};

  char* AsB = (char*)As;
  char* BsB = (char*)Bs;

  const bf16_t* pA0;
  const bf16_t* pB[2];
  {
    const int c = tid;
    const int r = c >> 3, sw = (c & 7) ^ (r & 7);
    pA0 = Lr.A + (size_t)(rowBase + r) * K + sw * 8;
  }
#pragma unroll
  for (int j = 0; j < 2; ++j) {
    const int c = j * 512 + tid;
    const int r = c >> 3, sw = (c & 7) ^ (r & 7);
    pB[j] = Lr.Bt + (size_t)(colBase + r) * K + sw * 8;
  }

  int aoff[2][2], boff[2][2];
#pragma unroll
  for (int m = 0; m < 2; ++m) {
    const int row = wrM * 32 + m * 16 + lo;
#pragma unroll
    for (int kk = 0; kk < 2; ++kk)
      aoff[m][kk] = row * 128 + (((kk * 4 + hi) ^ (row & 7)) << 4);
  }
#pragma unroll
  for (int n = 0; n < 2; ++n) {
    const int row = wcN * 32 + n * 16 + lo;
#pragma unroll
    for (int kk = 0; kk < 2; ++kk)
      boff[n][kk] = row * 128 + (((kk * 4 + hi) ^ (row & 7)) << 4);
  }

  const int waveB = wv * 1024;
  const int nkt = K >> 6;

  gload_lds16(pA0,   AsB + waveB);
  gload_lds16(pB[0], BsB + waveB);
  gload_lds16(pB[1], BsB + 8192 + waveB);
  __syncthreads();

  int cur = 0;
  for (int kt = 0; kt < nkt; ++kt) {
    const int curA = cur * 8192, curB = cur * 16384;
    if (kt + 1 < nkt) {
      const int ke = (kt + 1) * 64;
      gload_lds16(pA0 + ke,   AsB + (curA ^ 8192) + waveB);
      gload_lds16(pB[0] + ke, BsB + (curB ^ 16384) + waveB);
      gload_lds16(pB[1] + ke, BsB + (curB ^ 16384) + 8192 + waveB);
    }

    bf16x8 a[2][2], b[2][2];
#pragma unroll
    for (int m = 0; m < 2; ++m)
#pragma unroll
      for (int kk = 0; kk < 2; ++kk)
        a[m][kk] = *(const bf16x8*)(AsB + curA + aoff[m][kk]);
#pragma unroll
    for (int n = 0; n < 2; ++n)
#pragma unroll
      for (int kk = 0; kk < 2; ++kk)
        b[n][kk] = *(const bf16x8*)(BsB + curB + boff[n][kk]);

#pragma unroll
    for (int kk = 0; kk < 2; ++kk)
#pragma unroll
      for (int m = 0; m < 2; ++m)
#pragma unroll
        for (int n = 0; n < 2; ++n)
          acc[m][n] = __builtin_amdgcn_mfma_f32_16x16x32_bf16(a[m][kk], b[n][kk], acc[m][n], 0, 0, 0);

    if (kt + 1 < nkt) {
      __syncthreads();
      cur ^= 1;
    }
  }

  const int N = Lr.N;
#pragma unroll
  for (int m = 0; m < 2; ++m) {
#pragma unroll
    for (int n = 0; n < 2; ++n) {
#pragma unroll
      for (int r = 0; r < 4; ++r) {
        const int row = rowBase + wrM * 32 + m * 16 + hi * 4 + r;
        const int col = colBase + wcN * 32 + n * 16 + lo;
        const float v = acc[m][n][r];
        const size_t iN = (size_t)row * N + col;
        const size_t iO = (size_t)row * Lr.ostride + col;
        if (Lr.mode == 0) {
          Lr.O1[iO] = Lr.X[iN] - tanhf(v);
        } else {
          Lr.O1[iO] = Lr.X[iN] - v;
        }
      }
    }
  }
}

// ======================= prep kernels =======================
__global__ void prep_all(const float* __restrict__ W, bf16_t* __restrict__ WTb,
                         uint8_t* __restrict__ W8, uint8_t* __restrict__ WT8,
                         int R, int C) {
  __shared__ float t[64][65];
  const int tx = threadIdx.x, ty = threadIdx.y;  // (64,4)
  const int c0 = blockIdx.x * 64, r0 = blockIdx.y * 64;
  for (int rr = ty; rr < 64; rr += 4) {
    const float v = W[(size_t)(r0 + rr) * C + c0 + tx];
    W8[(size_t)(r0 + rr) * C + c0 + tx] = f2fp8(v * S8);
    t[rr][tx] = v;
  }
  __syncthreads();
  for (int rr = ty; rr < 64; rr += 4) {
    const float v = t[tx][rr];
    WTb[(size_t)(c0 + rr) * R + r0 + tx] = __float2bfloat16(v);
    WT8[(size_t)(c0 + rr) * R + r0 + tx] = f2fp8(v * S8);
  }
}

__global__ void copy_cast3(const float* __restrict__ in, float* __restrict__ of,
                           uint8_t* __restrict__ o8, bf16_t* __restrict__ ob, int n) {
  const int i = blockIdx.x * blockDim.x + threadIdx.x;
  if (i < n) {
    const float v = in[i];
    of[i] = v;
    o8[i] = f2fp8(v * S8);
    ob[i] = __float2bfloat16(v);
  }
}

__global__ void copy_e0(const float* __restrict__ mu0, float* __restrict__ out) {
  const int i = blockIdx.x * blockDim.x + threadIdx.x;
  if (i < 512 * 1024) {
    const int b = i >> 10, j = i & 1023;
    out[(size_t)b * 12288 + j] = mu0[i];
  }
}

extern "C" void kernel_launch(void* const* d_in, const int* in_sizes, int n_in,
                              void* d_out, int out_size, void* d_ws, size_t ws_size,
                              hipStream_t stream) {
  const float* img  = (const float*)d_in[0];
  const float* mu0i = (const float*)d_in[1];
  const float* mu1i = (const float*)d_in[2];
  const float* mu2i = (const float*)d_in[3];
  const float* W0   = (const float*)d_in[4];
  const float* W1   = (const float*)d_in[5];
  const float* W2   = (const float*)d_in[6];
  float* out = (float*)d_out;
  const int n_iters = 20;  // fixed by setup_inputs

  // ---- workspace carve ----
  char* p = (char*)d_ws;
  auto alloc = [&](size_t bytes) -> char* {
    char* r = p;
    p += (bytes + 255) & ~(size_t)255;
    return r;
  };
  bf16_t* WT0 = (bf16_t*)alloc((size_t)4096 * 1024 * 2);
  bf16_t* WT1 = (bf16_t*)alloc((size_t)4096 * 4096 * 2);
  bf16_t* WT2 = (bf16_t*)alloc((size_t)3072 * 4096 * 2);
  uint8_t* W80  = (uint8_t*)alloc((size_t)1024 * 4096);
  uint8_t* W81  = (uint8_t*)alloc((size_t)4096 * 4096);
  uint8_t* W82  = (uint8_t*)alloc((size_t)4096 * 3072);
  uint8_t* WT80 = (uint8_t*)alloc((size_t)4096 * 1024);
  uint8_t* WT81 = (uint8_t*)alloc((size_t)4096 * 4096);
  uint8_t* WT82 = (uint8_t*)alloc((size_t)3072 * 4096);
  float*   mu0 = (float*)alloc((size_t)512 * 1024 * 4);
  float*   mu1 = (float*)alloc((size_t)512 * 4096 * 4);
  float*   mu2 = (float*)alloc((size_t)512 * 4096 * 4);
  uint8_t* m80 = (uint8_t*)alloc((size_t)512 * 1024);
  uint8_t* m81 = (uint8_t*)alloc((size_t)512 * 4096);
  uint8_t* m82 = (uint8_t*)alloc((size_t)512 * 4096);
  bf16_t*  mb0 = (bf16_t*)alloc((size_t)512 * 1024 * 2);
  bf16_t*  mb1 = (bf16_t*)alloc((size_t)512 * 4096 * 2);
  bf16_t*  mb2 = (bf16_t*)alloc((size_t)512 * 4096 * 2);
  float*   e1  = (float*)alloc((size_t)512 * 4096 * 4);
  float*   e2  = (float*)alloc((size_t)512 * 4096 * 4);
  float*   e3  = (float*)alloc((size_t)512 * 3072 * 4);
  uint8_t* G80 = (uint8_t*)alloc((size_t)512 * 4096);
  uint8_t* G81 = (uint8_t*)alloc((size_t)512 * 4096);
  uint8_t* G82 = (uint8_t*)alloc((size_t)512 * 3072);
  (void)ws_size;

  // ---- prep ----
  dim3 tb(64, 4);
  prep_all<<<dim3(4096 / 64, 1024 / 64), tb, 0, stream>>>(W0, WT0, W80, WT80, 1024, 4096);
  prep_all<<<dim3(4096 / 64, 4096 / 64), tb, 0, stream>>>(W1, WT1, W81, WT81, 4096, 4096);
  prep_all<<<dim3(3072 / 64, 4096 / 64), tb, 0, stream>>>(W2, WT2, W82, WT82, 4096, 3072);
  copy_cast3<<<(512 * 1024 + 255) / 256, 256, 0, stream>>>(mu0i, mu0, m80, mb0, 512 * 1024);
  copy_cast3<<<(512 * 4096 + 255) / 256, 256, 0, stream>>>(mu1i, mu1, m81, mb1, 512 * 4096);
  copy_cast3<<<(512 * 4096 + 255) / 256, 256, 0, stream>>>(mu2i, mu2, m82, mb2, 512 * 4096);

  const Seg SENT = { 1 << 30, 0, 0, 1, 1 };

  // ---- fp8 forward: UNIFORM 32-step jobs, grid 512 = 2/CU, makespan 64.
  // L1 256 jobs (ids 0-255), L2 192 (256-447), L0-merged 64 (448-511,
  // each loops 4 tn sub-tiles of 8 steps). CU 0-191: L1+L2; 192-255: L1+L0m.
  GemmArgs8 fa;
  fa.L[0] = { m80, WT80, mu1, nullptr, e1, G80, nullptr, 1024, 4096, 0 };
  fa.L[1] = { m81, WT81, mu2, nullptr, e2, G81, nullptr, 4096, 4096, 0 };
  fa.L[2] = { m82, WT82, img, nullptr, e3, G82, nullptr, 4096, 3072, 1 };
  fa.seg[0] = { 0,   1, 0, 32, 1 };   // L1: 256
  fa.seg[1] = { 256, 2, 0, 24, 1 };   // L2: 192
  fa.seg[2] = { 448, 0, 0, 8,  4 };   // L0 merged: 64 blocks x 4 sub-tiles
  fa.seg[3] = SENT; fa.seg[4] = SENT; fa.seg[5] = SENT;
  fa.seg[6] = SENT; fa.seg[7] = SENT;
  const int fwdBlocks = 512;

  // ---- fp8 backward (R16 balanced tables, makespan 72) ----
  GemmArgs8 ba;
  ba.L[0] = { G80, W80, mu0, nullptr, mu0, m80, mb0, 4096, 1024, 2 };
  ba.L[1] = { G81, W81, mu1, e1,      mu1, m81, mb1, 4096, 4096, 3 };
  ba.L[2] = { G82, W82, mu2, e2,      mu2, m82, mb2, 3072, 4096, 3 };
  ba.seg[0] = { 0,   2, 0, 32, 1 };   // L2 tm0-1:  64
  ba.seg[1] = { 64,  1, 0, 32, 1 };   // L1 tm0-3: 128
  ba.seg[2] = { 192, 2, 6, 32, 1 };   // L2 tm6-7:  64
  ba.seg[3] = { 256, 2, 2, 32, 1 };   // L2 tm2-3:  64
  ba.seg[4] = { 320, 1, 4, 32, 1 };   // L1 tm4-7: 128
  ba.seg[5] = { 448, 0, 0, 8,  1 };   // L0 tm0-7:  64
  ba.seg[6] = { 512, 2, 4, 32, 1 };   // L2 tm4-5:  64
  ba.seg[7] = SENT;
  const int bwdBlocks = 576;

  // ---- bf16 final pass (errs straight into d_out, stride 12288) ----
  GemmArgs faF;
  faF.L[0] = { mb0, WT0, mu1, out + 1024, 1024, 4096, 12288, 0 };
  faF.L[1] = { mb1, WT1, mu2, out + 5120, 4096, 4096, 12288, 0 };
  faF.L[2] = { mb2, WT2, img, out + 9216, 4096, 3072, 12288, 1 };
  faF.seg[0] = { 0,   0, 0, 32, 1 };
  faF.seg[1] = { 256, 1, 0, 32, 1 };
  faF.seg[2] = { 512, 2, 0, 24, 1 };
  faF.seg[3] = SENT; faF.seg[4] = SENT; faF.seg[5] = SENT;
  faF.seg[6] = SENT; faF.seg[7] = SENT;

  // ---- iterate ----
  for (int it = 0; it < n_iters; ++it) {
    gemm_fp8<<<fwdBlocks, 512, 0, stream>>>(fa);
    gemm_fp8<<<bwdBlocks, 512, 0, stream>>>(ba);
  }
  gemm_bf16<<<704, 512, 0, stream>>>(faF);
  copy_e0<<<(512 * 1024 + 255) / 256, 256, 0, stream>>>(mu0, out);
}

// Round 20
// 2220.660 us; speedup vs baseline: 1.2662x; 1.2662x over previous
//
#include <hip/hip_runtime.h>
#include <hip/hip_bf16.h>
#include <hip/hip_fp8.h>
#include <stdint.h>

typedef __hip_bfloat16 bf16_t;
typedef __attribute__((ext_vector_type(8))) short bf16x8;
typedef __attribute__((ext_vector_type(4))) float f32x4;

#define MU_DT 0.01f
#define S8 8.0f                  // fp8 operand pre-scale (escape subnormals)
#define INV_S64 (1.0f / 64.0f)   // descale after fp8xfp8 GEMM

__device__ inline uint8_t f2fp8(float x) {
  __hip_fp8_e4m3 t(x);           // OCP e4m3 on gfx950
  return t.__x;
}

__device__ inline void gload_lds16(const void* g, void* lds) {
  __builtin_amdgcn_global_load_lds((const __attribute__((address_space(1))) void*)g,
                                   (__attribute__((address_space(3))) void*)lds, 16, 0, 0);
}

struct Seg { int start, layer, tmBase, tilesN; };

// ======================= fp8 iteration kernel (R16 verbatim) =======================
// R20 = exact restore of R16 (2222us best). R19's sub-job restructure
// regressed fp8 dispatches 52->66-80us with IDENTICAL job tables — the
// K-loop body's exact shape matters; do not restructure it.
// Engine: BM=64 x BN=128, BK=128 fp8, 8 waves, wave 32x32 of 16x16x32,
// dbuf 48KiB, issue-next-tile gload_lds FIRST then ds_read+MFMA then ONE
// __syncthreads per K-step. Swizzle slot^=row&7 on source + read (16B
// slots). Job tables: fwd/bwd makespan 72/72 = provable minimum for
// 3-blocks/CU packing. fp8 dispatches sit at the LDS-BW ceiling
// (~127 B/cy/CU vs 128 peak) for this geometry.
struct GemmLayer8 {
  const uint8_t* A;    // (512 x K) fp8(x8), row-major
  const uint8_t* Bt;   // (N x K) fp8(x8), row-major
  const float*  X;     // fwd: mu_{l+1}/img (f32); bwd: mu_l (f32)
  const float*  E;     // bwd l>0: e_l
  float*        O1;    // fwd: e out; bwd: mu out (f32 master)
  uint8_t*      O2a;   // fwd: G8 out; bwd: m8 out (fp8 x8)
  bf16_t*       O2b;   // bwd: mb out (bf16, for final pass)
  int K, N, mode;
};
struct GemmArgs8 { GemmLayer8 L[3]; Seg seg[8]; };

__global__ __launch_bounds__(512) void gemm_fp8(GemmArgs8 args) {
  __shared__ __align__(16) uint8_t As[2 * 64 * 128];    // 2 x 8 KiB
  __shared__ __align__(16) uint8_t Bs[2 * 128 * 128];   // 2 x 16 KiB

  const int bid = blockIdx.x;
  int s = 0;
#pragma unroll
  for (int i = 1; i < 8; ++i)
    if (bid >= args.seg[i].start) s = i;
  const Seg sg = args.seg[s];
  const GemmLayer8 Lr = args.L[sg.layer];
  const int local = bid - sg.start;
  const int tm = sg.tmBase + local / sg.tilesN;
  const int tn = local % sg.tilesN;
  const int K = Lr.K;
  const int rowBase = tm * 64;
  const int colBase = tn * 128;

  const int tid  = threadIdx.x;
  const int lane = tid & 63;
  const int wv   = tid >> 6;
  const int wrM  = wv >> 2;            // 0..1 -> 32-row band
  const int wcN  = wv & 3;             // 0..3 -> 32-col band
  const int lo   = lane & 15, hi = lane >> 4;

  f32x4 acc[2][2];
#pragma unroll
  for (int m = 0; m < 2; ++m)
#pragma unroll
    for (int n = 0; n < 2; ++n)
      acc[m][n] = f32x4{0.f, 0.f, 0.f, 0.f};

  char* AsB = (char*)As;   // halves at +0 / +8192
  char* BsB = (char*)Bs;   // halves at +0 / +16384

  // staging: per 16B-chunk c -> (row = c>>3, slot = c&7), elements = bytes
  const uint8_t* pA0;
  const uint8_t* pB[2];
  {
    const int c = tid;
    const int r = c >> 3, sw = (c & 7) ^ (r & 7);
    pA0 = Lr.A + (size_t)(rowBase + r) * K + sw * 16;
  }
#pragma unroll
  for (int j = 0; j < 2; ++j) {
    const int c = j * 512 + tid;
    const int r = c >> 3, sw = (c & 7) ^ (r & 7);
    pB[j] = Lr.Bt + (size_t)(colBase + r) * K + sw * 16;
  }

  // read-side: frag (m|n, kk): k = kk*32 + hi*8 (slot = kk*2 + hi/2, half = hi&1)
  int aoff[2][4], boff[2][4];
#pragma unroll
  for (int m = 0; m < 2; ++m) {
    const int row = wrM * 32 + m * 16 + lo;
#pragma unroll
    for (int kk = 0; kk < 4; ++kk)
      aoff[m][kk] = row * 128 + (((kk * 2 + (hi >> 1)) ^ (row & 7)) << 4) + ((hi & 1) << 3);
  }
#pragma unroll
  for (int n = 0; n < 2; ++n) {
    const int row = wcN * 32 + n * 16 + lo;
#pragma unroll
    for (int kk = 0; kk < 4; ++kk)
      boff[n][kk] = row * 128 + (((kk * 2 + (hi >> 1)) ^ (row & 7)) << 4) + ((hi & 1) << 3);
  }

  const int waveB = wv * 1024;
  const int nkt = K >> 7;   // BK=128; 8..32 steps

  gload_lds16(pA0,   AsB + waveB);
  gload_lds16(pB[0], BsB + waveB);
  gload_lds16(pB[1], BsB + 8192 + waveB);
  __syncthreads();

  int cur = 0;
  for (int kt = 0; kt < nkt; ++kt) {
    const int curA = cur * 8192, curB = cur * 16384;
    if (kt + 1 < nkt) {
      const int ke = (kt + 1) * 128;
      gload_lds16(pA0 + ke,   AsB + (curA ^ 8192) + waveB);
      gload_lds16(pB[0] + ke, BsB + (curB ^ 16384) + waveB);
      gload_lds16(pB[1] + ke, BsB + (curB ^ 16384) + 8192 + waveB);
    }

    long a[2][4], b[2][4];
#pragma unroll
    for (int m = 0; m < 2; ++m)
#pragma unroll
      for (int kk = 0; kk < 4; ++kk)
        a[m][kk] = *(const long*)(AsB + curA + aoff[m][kk]);
#pragma unroll
    for (int n = 0; n < 2; ++n)
#pragma unroll
      for (int kk = 0; kk < 4; ++kk)
        b[n][kk] = *(const long*)(BsB + curB + boff[n][kk]);

#pragma unroll
    for (int kk = 0; kk < 4; ++kk)
#pragma unroll
      for (int m = 0; m < 2; ++m)
#pragma unroll
        for (int n = 0; n < 2; ++n)
          acc[m][n] = __builtin_amdgcn_mfma_f32_16x16x32_fp8_fp8(a[m][kk], b[n][kk], acc[m][n], 0, 0, 0);

    if (kt + 1 < nkt) {
      __syncthreads();
      cur ^= 1;
    }
  }

  // epilogue — C/D layout: col = lane&15, row = (lane>>4)*4 + reg
  const int N = Lr.N;
#pragma unroll
  for (int m = 0; m < 2; ++m) {
#pragma unroll
    for (int n = 0; n < 2; ++n) {
#pragma unroll
      for (int r = 0; r < 4; ++r) {
        const int row = rowBase + wrM * 32 + m * 16 + hi * 4 + r;
        const int col = colBase + wcN * 32 + n * 16 + lo;
        const float v = acc[m][n][r] * INV_S64;
        const size_t iN = (size_t)row * N + col;
        if (Lr.mode == 0) {
          const float mu = Lr.X[iN];
          const float t  = tanhf(v);
          const float e  = mu - t;
          Lr.O1[iN]  = e;
          Lr.O2a[iN] = f2fp8(e * (1.0f - t * t) * S8);
        } else if (Lr.mode == 1) {
          const float e = Lr.X[iN] - v;
          Lr.O1[iN]  = e;
          Lr.O2a[iN] = f2fp8(e * S8);
        } else {
          const float mu = Lr.X[iN];
          const float sub = (Lr.mode == 2) ? mu : Lr.E[iN];
          const float nv = mu + MU_DT * (v - sub);
          Lr.O1[iN]  = nv;
          Lr.O2a[iN] = f2fp8(nv * S8);
          Lr.O2b[iN] = __float2bfloat16(nv);
        }
      }
    }
  }
}

// ======================= bf16 final-pass kernel =======================
// R16 engine; G-writes removed (final pass's G is never consumed;
// validated passing in R18/R19).
struct GemmLayer {
  const bf16_t* A;
  const bf16_t* Bt;
  const float*  X;
  float*        O1;
  int K, N, ostride, mode;
};
struct GemmArgs { GemmLayer L[3]; Seg seg[8]; };

__global__ __launch_bounds__(512) void gemm_bf16(GemmArgs args) {
  __shared__ __align__(16) bf16_t As[2 * 64 * 64];
  __shared__ __align__(16) bf16_t Bs[2 * 128 * 64];

  const int bid = blockIdx.x;
  int s = 0;
#pragma unroll
  for (int i = 1; i < 8; ++i)
    if (bid >= args.seg[i].start) s = i;
  const Seg sg = args.seg[s];
  const GemmLayer Lr = args.L[sg.layer];
  const int local = bid - sg.start;
  const int tm = sg.tmBase + local / sg.tilesN;
  const int tn = local % sg.tilesN;
  const int K = Lr.K;
  const int rowBase = tm * 64;
  const int colBase = tn * 128;

  const int tid  = threadIdx.x;
  const int lane = tid & 63;
  const int wv   = tid >> 6;
  const int wrM  = wv >> 2;
  const int wcN  = wv & 3;
  const int lo   = lane & 15, hi = lane >> 4;

  f32x4 acc[2][2];
#pragma unroll
  for (int m = 0; m < 2; ++m)
#pragma unroll
    for (int n = 0; n < 2; ++n)
      acc[m][n] = f32x4{0.f, 0.f, 0.f, 0.f};

  char* AsB = (char*)As;
  char* BsB = (char*)Bs;

  const bf16_t* pA0;
  const bf16_t* pB[2];
  {
    const int c = tid;
    const int r = c >> 3, sw = (c & 7) ^ (r & 7);
    pA0 = Lr.A + (size_t)(rowBase + r) * K + sw * 8;
  }
#pragma unroll
  for (int j = 0; j < 2; ++j) {
    const int c = j * 512 + tid;
    const int r = c >> 3, sw = (c & 7) ^ (r & 7);
    pB[j] = Lr.Bt + (size_t)(colBase + r) * K + sw * 8;
  }

  int aoff[2][2], boff[2][2];
#pragma unroll
  for (int m = 0; m < 2; ++m) {
    const int row = wrM * 32 + m * 16 + lo;
#pragma unroll
    for (int kk = 0; kk < 2; ++kk)
      aoff[m][kk] = row * 128 + (((kk * 4 + hi) ^ (row & 7)) << 4);
  }
#pragma unroll
  for (int n = 0; n < 2; ++n) {
    const int row = wcN * 32 + n * 16 + lo;
#pragma unroll
    for (int kk = 0; kk < 2; ++kk)
      boff[n][kk] = row * 128 + (((kk * 4 + hi) ^ (row & 7)) << 4);
  }

  const int waveB = wv * 1024;
  const int nkt = K >> 6;

  gload_lds16(pA0,   AsB + waveB);
  gload_lds16(pB[0], BsB + waveB);
  gload_lds16(pB[1], BsB + 8192 + waveB);
  __syncthreads();

  int cur = 0;
  for (int kt = 0; kt < nkt; ++kt) {
    const int curA = cur * 8192, curB = cur * 16384;
    if (kt + 1 < nkt) {
      const int ke = (kt + 1) * 64;
      gload_lds16(pA0 + ke,   AsB + (curA ^ 8192) + waveB);
      gload_lds16(pB[0] + ke, BsB + (curB ^ 16384) + waveB);
      gload_lds16(pB[1] + ke, BsB + (curB ^ 16384) + 8192 + waveB);
    }

    bf16x8 a[2][2], b[2][2];
#pragma unroll
    for (int m = 0; m < 2; ++m)
#pragma unroll
      for (int kk = 0; kk < 2; ++kk)
        a[m][kk] = *(const bf16x8*)(AsB + curA + aoff[m][kk]);
#pragma unroll
    for (int n = 0; n < 2; ++n)
#pragma unroll
      for (int kk = 0; kk < 2; ++kk)
        b[n][kk] = *(const bf16x8*)(BsB + curB + boff[n][kk]);

#pragma unroll
    for (int kk = 0; kk < 2; ++kk)
#pragma unroll
      for (int m = 0; m < 2; ++m)
#pragma unroll
        for (int n = 0; n < 2; ++n)
          acc[m][n] = __builtin_amdgcn_mfma_f32_16x16x32_bf16(a[m][kk], b[n][kk], acc[m][n], 0, 0, 0);

    if (kt + 1 < nkt) {
      __syncthreads();
      cur ^= 1;
    }
  }

  const int N = Lr.N;
#pragma unroll
  for (int m = 0; m < 2; ++m) {
#pragma unroll
    for (int n = 0; n < 2; ++n) {
#pragma unroll
      for (int r = 0; r < 4; ++r) {
        const int row = rowBase + wrM * 32 + m * 16 + hi * 4 + r;
        const int col = colBase + wcN * 32 + n * 16 + lo;
        const float v = acc[m][n][r];
        const size_t iN = (size_t)row * N + col;
        const size_t iO = (size_t)row * Lr.ostride + col;
        if (Lr.mode == 0) {
          Lr.O1[iO] = Lr.X[iN] - tanhf(v);
        } else {
          Lr.O1[iO] = Lr.X[iN] - v;
        }
      }
    }
  }
}

// ======================= prep kernels =======================
__global__ void prep_all(const float* __restrict__ W, bf16_t* __restrict__ WTb,
                         uint8_t* __restrict__ W8, uint8_t* __restrict__ WT8,
                         int R, int C) {
  __shared__ float t[64][65];
  const int tx = threadIdx.x, ty = threadIdx.y;  // (64,4)
  const int c0 = blockIdx.x * 64, r0 = blockIdx.y * 64;
  for (int rr = ty; rr < 64; rr += 4) {
    const float v = W[(size_t)(r0 + rr) * C + c0 + tx];
    W8[(size_t)(r0 + rr) * C + c0 + tx] = f2fp8(v * S8);
    t[rr][tx] = v;
  }
  __syncthreads();
  for (int rr = ty; rr < 64; rr += 4) {
    const float v = t[tx][rr];
    WTb[(size_t)(c0 + rr) * R + r0 + tx] = __float2bfloat16(v);
    WT8[(size_t)(c0 + rr) * R + r0 + tx] = f2fp8(v * S8);
  }
}

__global__ void copy_cast3(const float* __restrict__ in, float* __restrict__ of,
                           uint8_t* __restrict__ o8, bf16_t* __restrict__ ob, int n) {
  const int i = blockIdx.x * blockDim.x + threadIdx.x;
  if (i < n) {
    const float v = in[i];
    of[i] = v;
    o8[i] = f2fp8(v * S8);
    ob[i] = __float2bfloat16(v);
  }
}

__global__ void copy_e0(const float* __restrict__ mu0, float* __restrict__ out) {
  const int i = blockIdx.x * blockDim.x + threadIdx.x;
  if (i < 512 * 1024) {
    const int b = i >> 10, j = i & 1023;
    out[(size_t)b * 12288 + j] = mu0[i];
  }
}

extern "C" void kernel_launch(void* const* d_in, const int* in_sizes, int n_in,
                              void* d_out, int out_size, void* d_ws, size_t ws_size,
                              hipStream_t stream) {
  const float* img  = (const float*)d_in[0];
  const float* mu0i = (const float*)d_in[1];
  const float* mu1i = (const float*)d_in[2];
  const float* mu2i = (const float*)d_in[3];
  const float* W0   = (const float*)d_in[4];
  const float* W1   = (const float*)d_in[5];
  const float* W2   = (const float*)d_in[6];
  float* out = (float*)d_out;
  const int n_iters = 20;  // fixed by setup_inputs

  // ---- workspace carve ----
  char* p = (char*)d_ws;
  auto alloc = [&](size_t bytes) -> char* {
    char* r = p;
    p += (bytes + 255) & ~(size_t)255;
    return r;
  };
  bf16_t* WT0 = (bf16_t*)alloc((size_t)4096 * 1024 * 2);
  bf16_t* WT1 = (bf16_t*)alloc((size_t)4096 * 4096 * 2);
  bf16_t* WT2 = (bf16_t*)alloc((size_t)3072 * 4096 * 2);
  uint8_t* W80  = (uint8_t*)alloc((size_t)1024 * 4096);
  uint8_t* W81  = (uint8_t*)alloc((size_t)4096 * 4096);
  uint8_t* W82  = (uint8_t*)alloc((size_t)4096 * 3072);
  uint8_t* WT80 = (uint8_t*)alloc((size_t)4096 * 1024);
  uint8_t* WT81 = (uint8_t*)alloc((size_t)4096 * 4096);
  uint8_t* WT82 = (uint8_t*)alloc((size_t)3072 * 4096);
  float*   mu0 = (float*)alloc((size_t)512 * 1024 * 4);
  float*   mu1 = (float*)alloc((size_t)512 * 4096 * 4);
  float*   mu2 = (float*)alloc((size_t)512 * 4096 * 4);
  uint8_t* m80 = (uint8_t*)alloc((size_t)512 * 1024);
  uint8_t* m81 = (uint8_t*)alloc((size_t)512 * 4096);
  uint8_t* m82 = (uint8_t*)alloc((size_t)512 * 4096);
  bf16_t*  mb0 = (bf16_t*)alloc((size_t)512 * 1024 * 2);
  bf16_t*  mb1 = (bf16_t*)alloc((size_t)512 * 4096 * 2);
  bf16_t*  mb2 = (bf16_t*)alloc((size_t)512 * 4096 * 2);
  float*   e1  = (float*)alloc((size_t)512 * 4096 * 4);
  float*   e2  = (float*)alloc((size_t)512 * 4096 * 4);
  float*   e3  = (float*)alloc((size_t)512 * 3072 * 4);
  uint8_t* G80 = (uint8_t*)alloc((size_t)512 * 4096);
  uint8_t* G81 = (uint8_t*)alloc((size_t)512 * 4096);
  uint8_t* G82 = (uint8_t*)alloc((size_t)512 * 3072);
  (void)ws_size;

  // ---- prep ----
  dim3 tb(64, 4);
  prep_all<<<dim3(4096 / 64, 1024 / 64), tb, 0, stream>>>(W0, WT0, W80, WT80, 1024, 4096);
  prep_all<<<dim3(4096 / 64, 4096 / 64), tb, 0, stream>>>(W1, WT1, W81, WT81, 4096, 4096);
  prep_all<<<dim3(3072 / 64, 4096 / 64), tb, 0, stream>>>(W2, WT2, W82, WT82, 4096, 3072);
  copy_cast3<<<(512 * 1024 + 255) / 256, 256, 0, stream>>>(mu0i, mu0, m80, mb0, 512 * 1024);
  copy_cast3<<<(512 * 4096 + 255) / 256, 256, 0, stream>>>(mu1i, mu1, m81, mb1, 512 * 4096);
  copy_cast3<<<(512 * 4096 + 255) / 256, 256, 0, stream>>>(mu2i, mu2, m82, mb2, 512 * 4096);

  const Seg SENT = { 1 << 30, 0, 0, 1 };

  // ---- fp8 forward (R16 tables: makespan 72 = provable min) ----
  GemmArgs8 fa;
  fa.L[0] = { m80, WT80, mu1, nullptr, e1, G80, nullptr, 1024, 4096, 0 };
  fa.L[1] = { m81, WT81, mu2, nullptr, e2, G81, nullptr, 4096, 4096, 0 };
  fa.L[2] = { m82, WT82, img, nullptr, e3, G82, nullptr, 4096, 3072, 1 };
  fa.seg[0] = { 0,   0, 0, 32 };
  fa.seg[1] = { 256, 1, 0, 32 };
  fa.seg[2] = { 512, 2, 0, 24 };
  fa.seg[3] = SENT; fa.seg[4] = SENT; fa.seg[5] = SENT;
  fa.seg[6] = SENT; fa.seg[7] = SENT;
  const int fwdBlocks = 704;

  // ---- fp8 backward (R16 balanced tables: makespan 72 = provable min) ----
  GemmArgs8 ba;
  ba.L[0] = { G80, W80, mu0, nullptr, mu0, m80, mb0, 4096, 1024, 2 };
  ba.L[1] = { G81, W81, mu1, e1,      mu1, m81, mb1, 4096, 4096, 3 };
  ba.L[2] = { G82, W82, mu2, e2,      mu2, m82, mb2, 3072, 4096, 3 };
  ba.seg[0] = { 0,   2, 0, 32 };   // L2 tm0-1:  64
  ba.seg[1] = { 64,  1, 0, 32 };   // L1 tm0-3: 128
  ba.seg[2] = { 192, 2, 6, 32 };   // L2 tm6-7:  64
  ba.seg[3] = { 256, 2, 2, 32 };   // L2 tm2-3:  64
  ba.seg[4] = { 320, 1, 4, 32 };   // L1 tm4-7: 128
  ba.seg[5] = { 448, 0, 0, 8 };    // L0 tm0-7:  64
  ba.seg[6] = { 512, 2, 4, 32 };   // L2 tm4-5:  64
  ba.seg[7] = SENT;
  const int bwdBlocks = 576;

  // ---- bf16 final pass (errs straight into d_out, stride 12288) ----
  GemmArgs faF;
  faF.L[0] = { mb0, WT0, mu1, out + 1024, 1024, 4096, 12288, 0 };
  faF.L[1] = { mb1, WT1, mu2, out + 5120, 4096, 4096, 12288, 0 };
  faF.L[2] = { mb2, WT2, img, out + 9216, 4096, 3072, 12288, 1 };
  faF.seg[0] = { 0,   0, 0, 32 };
  faF.seg[1] = { 256, 1, 0, 32 };
  faF.seg[2] = { 512, 2, 0, 24 };
  faF.seg[3] = SENT; faF.seg[4] = SENT; faF.seg[5] = SENT;
  faF.seg[6] = SENT; faF.seg[7] = SENT;

  // ---- iterate ----
  for (int it = 0; it < n_iters; ++it) {
    gemm_fp8<<<fwdBlocks, 512, 0, stream>>>(fa);
    gemm_fp8<<<bwdBlocks, 512, 0, stream>>>(ba);
  }
  gemm_bf16<<<704, 512, 0, stream>>>(faF);
  copy_e0<<<(512 * 1024 + 255) / 256, 256, 0, stream>>>(mu0, out);
}